// Round 12
// baseline (174.275 us; speedup 1.0000x reference)
//
#include <hip/hip_runtime.h>
#include <hip/hip_fp16.h>

// LightGCN propagation on MI355X (gfx950).
//   h_{k+1}[r,:] = sum_{e: row[e]==r} val[e] * h_k[col[e],:]   D=32
//   out = (x + h1 + h2 + h3) / 4
//
// Round 21: R20 confirmed (174.3). spmm (3 x ~40 us) is latency-bound:
// per-layer L2-miss traffic is only ~58 MB (~5-10 us at L3 rates), but a
// max-deg-25 group serially runs 4 gather rounds (8+8+4+1) with just 8
// gathers in flight, plus divergent tail paths. Fix: UNIFORM MASKED
// 8-edge batches with a 2-deep ping-pong register pipeline -- 16 gathers
// outstanding for every row, one code path, no tails. Dead slots clamp
// the edge index to e-1 (re-hits the row's last line: no new traffic) and
// mask val to 0 (bit-identical sums). Critical path rounds ~4 -> ~2.
// Everything else unchanged from R20 (compressed 4 B edges, bf16-table-
// only mid layers, fused cvt, dual-scan scatter, wave-privatized sort).

#define NN 100000
#define NE 1600000
#define DD 32
#define CHUNK 4096
#define NCHUNK ((NE + CHUNK - 1) / CHUNK)   // 391
#define BROWS 128
#define NBKT ((NN + BROWS - 1) / BROWS)     // 782
#define LDSE 3072                           // LDS staging cap in bucket_sort

__device__ __forceinline__ unsigned f2bf(float f) {
    unsigned u = __float_as_uint(f);
    return (u + 0x7fffu + ((u >> 16) & 1u)) >> 16;   // RNE
}

// val (>=0) -> 15-bit fp16 payload
__device__ __forceinline__ unsigned f2h15(float v) {
    return (unsigned)__half_as_ushort(__float2half(v)) & 0x7fffu;
}
// 15-bit fp16 payload -> float
__device__ __forceinline__ float h152f(unsigned u) {
    return __half2float(__ushort_as_half((unsigned short)(u & 0x7fffu)));
}

#define BF_LO(u) __uint_as_float((u) << 16)
#define BF_HI(u) __uint_as_float((u) & 0xffff0000u)

// ---- pass 1: per-chunk bucket histogram matrix H[c][b] (coalesced) -------

__global__ __launch_bounds__(1024) void hist_kernel(
    const int* __restrict__ row, int* __restrict__ H)
{
    __shared__ int cnt[NBKT];
    const int tid = threadIdx.x;
    const int start = blockIdx.x * CHUNK;
    const int n = min(CHUNK, NE - start);
    for (int k = tid; k < NBKT; k += 1024) cnt[k] = 0;
    __syncthreads();
    const int j = tid * 4;                       // 4 edges per thread
    if (j + 3 < n) {
        int4 r4 = *(const int4*)(row + start + j);
        atomicAdd(&cnt[r4.x >> 7], 1);
        atomicAdd(&cnt[r4.y >> 7], 1);
        atomicAdd(&cnt[r4.z >> 7], 1);
        atomicAdd(&cnt[r4.w >> 7], 1);
    } else {
        for (int k = j; k < n; k++) atomicAdd(&cnt[row[start + k] >> 7], 1);
    }
    __syncthreads();
    int* Hrow = H + (size_t)blockIdx.x * NBKT;
    for (int k = tid; k < NBKT; k += 1024) Hrow[k] = cnt[k];   // coalesced
}

// ---- pass 2: wave-parallel per-bucket scan over chunks -------------------

__global__ __launch_bounds__(1024) void scan_tr_kernel(
    const int* __restrict__ H, int* __restrict__ Pt, int* __restrict__ tot)
{
    const int b = blockIdx.x * 16 + (threadIdx.x >> 6);
    if (b >= NBKT) return;
    const int lane = threadIdx.x & 63;
    int run = 0;
    #pragma unroll
    for (int c0 = 0; c0 < NCHUNK; c0 += 64) {
        int c = c0 + lane;
        int v = (c < NCHUNK) ? H[(size_t)c * NBKT + b] : 0;
        int x = v;
        #pragma unroll
        for (int off = 1; off < 64; off <<= 1) {
            int y = __shfl_up(x, off, 64);
            if (lane >= off) x += y;
        }
        if (c < NCHUNK) Pt[(size_t)b * NCHUNK + c] = run + x - v;  // exclusive
        run += __shfl(x, 63, 64);                 // wave total
    }
    if (lane == 0) tot[b] = run;
}

// ---- pass 3: multisplit scatter; dual scan (cnt, tot) -> lbase+bucketbase
// record: ((row & 127) << 17) | col   (col < 2^17), val bits in .y

__global__ __launch_bounds__(1024) void scatter_kernel(
    const int* __restrict__ row, const int* __restrict__ col,
    const float* __restrict__ val, const int* __restrict__ tot,
    const int* __restrict__ Pt, int2* __restrict__ tmp,
    int* __restrict__ bucketbase_g)
{
    __shared__ int cnt[NBKT];      // 3.1 KB
    __shared__ int lbase[NBKT];    // 3.1 KB  chunk-local exclusive scan
    __shared__ int gofs[NBKT];     // 3.1 KB  global base per bucket
    __shared__ int wtA[16], wtB[16];
    __shared__ int2 recs[CHUNK];   // 32 KB   records in bucket order
    __shared__ int dest[CHUNK];    // 16 KB   global dst per sorted position
    const int tid = threadIdx.x;
    const int start = blockIdx.x * CHUNK;
    const int n = min(CHUNK, NE - start);
    for (int k = tid; k < NBKT; k += 1024) cnt[k] = 0;
    __syncthreads();

    int rrow[CHUNK / 1024], rcol[CHUNK / 1024], rank[CHUNK / 1024];
    float rval[CHUNK / 1024];
    #pragma unroll
    for (int k = 0; k < CHUNK / 1024; k++) {
        int j = k * 1024 + tid;
        if (j < n) {
            int r = row[start + j];
            rrow[k] = r;
            rcol[k] = col[start + j];
            rval[k] = val[start + j];
            rank[k] = atomicAdd(&cnt[r >> 7], 1);
        } else {
            rrow[k] = -1;
        }
    }
    __syncthreads();

    // dual block-exclusive scan: cnt -> lbase ; tot -> bucketbase
    int v1 = (tid < NBKT) ? cnt[tid] : 0;
    int v2 = (tid < NBKT) ? tot[tid] : 0;
    {
        int lane = tid & 63, w = tid >> 6;
        int x1 = v1, x2 = v2;
        #pragma unroll
        for (int off = 1; off < 64; off <<= 1) {
            int y1 = __shfl_up(x1, off, 64);
            int y2 = __shfl_up(x2, off, 64);
            if (lane >= off) { x1 += y1; x2 += y2; }
        }
        if (lane == 63) { wtA[w] = x1; wtB[w] = x2; }
        __syncthreads();
        if (w == 0 && lane < 16) {
            int y1 = wtA[lane], y2 = wtB[lane];
            #pragma unroll
            for (int off = 1; off < 16; off <<= 1) {
                int z1 = __shfl_up(y1, off, 16);
                int z2 = __shfl_up(y2, off, 16);
                if ((lane & 15) >= off) { y1 += z1; y2 += z2; }
            }
            wtA[lane] = y1; wtB[lane] = y2;
        }
        __syncthreads();
        int e1 = x1 + ((w > 0) ? wtA[w - 1] : 0) - v1;
        int e2 = x2 + ((w > 0) ? wtB[w - 1] : 0) - v2;
        if (tid < NBKT) {
            lbase[tid] = e1;
            gofs[tid] = e2 + Pt[(size_t)tid * NCHUNK + blockIdx.x];
            if (blockIdx.x == 0) bucketbase_g[tid] = e2;
        }
        if (blockIdx.x == 0 && tid == NBKT) bucketbase_g[NBKT] = NE;
    }
    __syncthreads();

    #pragma unroll
    for (int k = 0; k < CHUNK / 1024; k++) {
        if (rrow[k] >= 0) {
            int b = rrow[k] >> 7;
            int p = lbase[b] + rank[k];
            recs[p] = make_int2(((rrow[k] & 127) << 17) | rcol[k],
                                __float_as_int(rval[k]));
            dest[p] = gofs[b] + rank[k];
        }
    }
    __syncthreads();

    for (int p = tid; p < n; p += 1024)        // run-contiguous stores
        tmp[dest[p]] = recs[p];
}

// ---- pass 4: per-bucket row sort (wave-privatized) + fused cvt -----------
// Emits COMPRESSED edges: u32 = (col << 15) | fp16bits(val)  (val >= 0).
// Block b also converts x rows [b*128, b*128+128) to the bf16 table.
// Writes row_ptr for r <= NN (covers row_ptr[NN] = NE).

__global__ __launch_bounds__(512) void bucket_sort_kernel(
    const int* __restrict__ bucketbase, const int2* __restrict__ tmp,
    int* __restrict__ row_ptr, unsigned* __restrict__ edges,
    const float2* __restrict__ xin2, unsigned* __restrict__ hb0)
{
    __shared__ int cntw[8][BROWS];   // 4 KB  per-wave counts
    __shared__ int curw[8][BROWS];   // 4 KB  per-wave cursors
    __shared__ int wt2[2];
    __shared__ unsigned ed[LDSE];    // 12 KB staging (compressed records)
    const int tid = threadIdx.x;
    const int w   = tid >> 6;        // wave id 0..7
    const int b   = blockIdx.x;
    const int s   = bucketbase[b];
    const int e   = bucketbase[b + 1];
    const int tot = e - s;

    // fused cvt: this bucket's 128 rows = 2048 float2 words
    #pragma unroll
    for (int k = 0; k < 4; k++) {
        int j = b * 2048 + k * 512 + tid;
        if (j < NN * 16) {
            float2 f = xin2[j];
            hb0[j] = f2bf(f.x) | (f2bf(f.y) << 16);
        }
    }

    for (int k = tid; k < 8 * BROWS; k += 512) (&cntw[0][0])[k] = 0;
    __syncthreads();

    int2 rc[6];
    #pragma unroll
    for (int k = 0; k < 6; k++) {
        int j = s + k * 512 + tid;
        rc[k] = (j < e && j < s + LDSE) ? tmp[j] : make_int2(-1, 0);
        if (rc[k].x >= 0) atomicAdd(&cntw[w][rc[k].x >> 17], 1);
    }
    if (tot > LDSE)                                        // fallback count
        for (int j = s + LDSE + tid; j < e; j += 512)
            atomicAdd(&cntw[w][tmp[j].x >> 17], 1);
    __syncthreads();

    // deg per row, block-exclusive scan -> per-wave cursors + row_ptr
    int v = 0, x = 0;
    if (tid < BROWS) {
        int d = 0;
        #pragma unroll
        for (int ww = 0; ww < 8; ww++) d += cntw[ww][tid];
        v = d;
        int lane = tid & 63;
        x = v;
        #pragma unroll
        for (int off = 1; off < 64; off <<= 1) {
            int y = __shfl_up(x, off, 64);
            if (lane >= off) x += y;
        }
        if (lane == 63) wt2[tid >> 6] = x;
    }
    __syncthreads();
    if (tid < BROWS) {
        int excl = x + ((tid >> 6) ? wt2[0] : 0) - v;
        int r = b * BROWS + tid;
        if (r <= NN) row_ptr[r] = s + excl;      // r==NN -> NE (last bucket)
        int run = excl;
        #pragma unroll
        for (int ww = 0; ww < 8; ww++) { curw[ww][tid] = run; run += cntw[ww][tid]; }
    }
    __syncthreads();

    if (tot <= LDSE) {
        #pragma unroll
        for (int k = 0; k < 6; k++) {
            if (rc[k].x >= 0) {
                int pos = atomicAdd(&curw[w][rc[k].x >> 17], 1);
                ed[pos] = ((unsigned)(rc[k].x & 0x1FFFF) << 15)
                        | f2h15(__int_as_float(rc[k].y));
            }
        }
        __syncthreads();
        for (int k = tid; k < tot; k += 512)     // coalesced write-back
            edges[s + k] = ed[k];
    } else {
        // fallback (statistically unreachable: bucket > 3072)
        #pragma unroll
        for (int k = 0; k < 6; k++) {
            if (rc[k].x >= 0) {
                int pos = atomicAdd(&curw[w][rc[k].x >> 17], 1);
                edges[s + pos] = ((unsigned)(rc[k].x & 0x1FFFF) << 15)
                               | f2h15(__int_as_float(rc[k].y));
            }
        }
        for (int j = s + LDSE + tid; j < e; j += 512) {
            int2 rec = tmp[j];
            int pos = atomicAdd(&curw[w][rec.x >> 17], 1);
            edges[s + pos] = ((unsigned)(rec.x & 0x1FFFF) << 15)
                           | f2h15(__int_as_float(rec.y));
        }
    }
}

// ---- SpMM: 4-lane group per row, uniform masked batches, 2-deep pipe -----
// Lane t in [0,4) owns feats [8t, 8t+8). Edges are 4 B compressed
// (col<<15 | fp16 val). Fixed 8-edge batches; slots past e clamp the edge
// index to e-1 (re-hit last line, no new traffic) and mask val to 0 --
// bit-identical sums, single code path, 16 gathers in flight per group.
// FINAL==0: houtb = bf16(A h)                      (mid layers 1,2)
// FINAL==1: out = (x + h1b + h2b + A h2) * 0.25    (h1b4 = h1 table rows)

template <int FINAL>
__global__ __launch_bounds__(256) void spmm_kernel(
    const int* __restrict__ row_ptr, const unsigned* __restrict__ edges,
    const uint4* __restrict__ hb4,               // gather table (4 uint4/row)
    uint4* __restrict__ houtb4,                  // next bf16 table (mid)
    const uint4* __restrict__ h1b4,              // h1 table rows (final)
    const float4* __restrict__ xin4, float4* __restrict__ out4)
{
    const int g = blockIdx.x * 64 + (threadIdx.x >> 2);   // row
    if (g >= NN) return;
    const int t = threadIdx.x & 3;
    const int s = row_ptr[g];
    const int e = row_ptr[g + 1];
    const int o = g * 8 + t * 2;                 // epilogue float4 index

    // prefetch epilogue inputs (independent of the edge loop)
    float4 p0, p1; uint4 q1, q2;
    if (FINAL) {
        p0 = xin4[o]; p1 = xin4[o + 1];
        q1 = h1b4[g * 4 + t];                    // h1 bf16 row chunk
        q2 = hb4[g * 4 + t];                     // h2 bf16 row chunk
    }

    float acc[8] = {0.f, 0.f, 0.f, 0.f, 0.f, 0.f, 0.f, 0.f};

#define ACC8(W, V)                                                         \
    do {                                                                   \
        acc[0] += (V) * BF_LO((W).x);                                      \
        acc[1] += (V) * BF_HI((W).x);                                      \
        acc[2] += (V) * BF_LO((W).y);                                      \
        acc[3] += (V) * BF_HI((W).y);                                      \
        acc[4] += (V) * BF_LO((W).z);                                      \
        acc[5] += (V) * BF_HI((W).z);                                      \
        acc[6] += (V) * BF_LO((W).w);                                      \
        acc[7] += (V) * BF_HI((W).w);                                      \
    } while (0)

// load masked batch at base S0 into (v_, w_); dead slots re-read edges[e-1]
#define LOADB(S0, v_, w_)                                                  \
    _Pragma("unroll")                                                      \
    for (int k = 0; k < 8; ++k) {                                          \
        int j = (S0) + k;                                                  \
        unsigned uu = edges[min(j, e - 1)];                                \
        v_[k] = (j < e) ? h152f(uu) : 0.f;                                 \
        w_[k] = hb4[(uu >> 15) * 4 + t];                                   \
    }

#define CONSB(v_, w_)                                                      \
    _Pragma("unroll")                                                      \
    for (int k = 0; k < 8; ++k) ACC8(w_[k], v_[k]);

    const int deg = e - s;
    const int nb = (deg + 7) >> 3;               // number of 8-edge batches
    if (nb > 0) {
        float vA[8], vB[8]; uint4 wA[8], wB[8];
        LOADB(s,     vA, wA);                    // batch 0
        LOADB(s + 8, vB, wB);                    // batch 1 (masked if nb==1)
        int b = 0;
        for (; b + 2 <= nb; b += 2) {
            CONSB(vA, wA); LOADB(s + 8 * (b + 2), vA, wA);
            CONSB(vB, wB); LOADB(s + 8 * (b + 3), vB, wB);
        }
        if (b < nb) CONSB(vA, wA);               // nb odd: last batch in A
    }
#undef LOADB
#undef CONSB
#undef ACC8

    if (!FINAL) {
        // mid layer: write next bf16 table only
        uint4 p;
        p.x = f2bf(acc[0]) | (f2bf(acc[1]) << 16);
        p.y = f2bf(acc[2]) | (f2bf(acc[3]) << 16);
        p.z = f2bf(acc[4]) | (f2bf(acc[5]) << 16);
        p.w = f2bf(acc[6]) | (f2bf(acc[7]) << 16);
        houtb4[g * 4 + t] = p;
    } else {
        // final: out = (x + h1b + h2b + acc) * 0.25
        float4 lo, hi;
        lo.x = (p0.x + BF_LO(q1.x) + BF_LO(q2.x) + acc[0]) * 0.25f;
        lo.y = (p0.y + BF_HI(q1.x) + BF_HI(q2.x) + acc[1]) * 0.25f;
        lo.z = (p0.z + BF_LO(q1.y) + BF_LO(q2.y) + acc[2]) * 0.25f;
        lo.w = (p0.w + BF_HI(q1.y) + BF_HI(q2.y) + acc[3]) * 0.25f;
        hi.x = (p1.x + BF_LO(q1.z) + BF_LO(q2.z) + acc[4]) * 0.25f;
        hi.y = (p1.y + BF_HI(q1.z) + BF_HI(q2.z) + acc[5]) * 0.25f;
        hi.z = (p1.z + BF_LO(q1.w) + BF_LO(q2.w) + acc[6]) * 0.25f;
        hi.w = (p1.w + BF_HI(q1.w) + BF_HI(q2.w) + acc[7]) * 0.25f;
        out4[o] = lo;
        out4[o + 1] = hi;
    }
}

// ---- launch ---------------------------------------------------------------

extern "C" void kernel_launch(void* const* d_in, const int* in_sizes, int n_in,
                              void* d_out, int out_size, void* d_ws, size_t ws_size,
                              hipStream_t stream) {
    const int*   edge_row = (const int*)d_in[0];
    const int*   edge_col = (const int*)d_in[1];
    const float* edge_val = (const float*)d_in[2];
    const float* x        = (const float*)d_in[3];
    float* out = (float*)d_out;

    char* ws = (char*)d_ws;
    int*  H          = (int*)ws;   ws += (((size_t)NCHUNK * NBKT * 4) + 511) & ~511ull; // 1.22 MB
    int*  Pt         = (int*)ws;   ws += (((size_t)NBKT * NCHUNK * 4) + 511) & ~511ull; // 1.22 MB
    int*  tot        = (int*)ws;   ws += 4096;
    int*  bucketbase = (int*)ws;   ws += 4096;
    int*  row_ptr    = (int*)ws;   ws += ((size_t)(NN + 1) * 4 + 511) & ~511ull;
    int2* tmp        = (int2*)ws;  ws += (size_t)NE * 8 + 64;   // 12.8 MB
    unsigned* edges  = (unsigned*)ws; ws += (size_t)NE * 4 + 64; // 6.4 MB compressed
    unsigned* hb0    = (unsigned*)ws;  ws += (size_t)NN * DD * 2;  // 6.4 MB bf16
    unsigned* hb1    = (unsigned*)ws;  ws += (size_t)NN * DD * 2;  // 6.4 MB bf16
    unsigned* hb2    = (unsigned*)ws;  ws += (size_t)NN * DD * 2;  // 6.4 MB bf16

    hist_kernel       <<<NCHUNK, 1024, 0, stream>>>(edge_row, H);
    scan_tr_kernel    <<<(NBKT + 15) / 16, 1024, 0, stream>>>(H, Pt, tot);
    scatter_kernel    <<<NCHUNK, 1024, 0, stream>>>(edge_row, edge_col, edge_val,
                                                    tot, Pt, tmp, bucketbase);
    bucket_sort_kernel<<<NBKT, 512, 0, stream>>>(bucketbase, tmp, row_ptr, edges,
                                                 (const float2*)x, hb0);

    dim3 sp_grid((NN + 63) / 64);   // 1563 blocks, 4 lanes/row, 64 rows/block
    // layer 1: h1b = bf16(A x)
    spmm_kernel<0><<<sp_grid, 256, 0, stream>>>(row_ptr, edges,
        (const uint4*)hb0, (uint4*)hb1, nullptr, nullptr, nullptr);
    // layer 2: h2b = bf16(A h1)
    spmm_kernel<0><<<sp_grid, 256, 0, stream>>>(row_ptr, edges,
        (const uint4*)hb1, (uint4*)hb2, nullptr, nullptr, nullptr);
    // layer 3: out = (x + h1b + h2b + A h2) / 4
    spmm_kernel<1><<<sp_grid, 256, 0, stream>>>(row_ptr, edges,
        (const uint4*)hb2, nullptr, (const uint4*)hb1,
        (const float4*)x, (float4*)out);
}